// Round 2
// baseline (565.197 us; speedup 1.0000x reference)
//
#include <hip/hip_runtime.h>
#include <stdint.h>

typedef unsigned short u16;
typedef unsigned long long u64;
typedef __bf16 bf16x8 __attribute__((ext_vector_type(8)));
typedef float f32x4 __attribute__((ext_vector_type(4)));

#define MFMA16(a, b, c) __builtin_amdgcn_mfma_f32_16x16x32_bf16((a), (b), (c), 0, 0, 0)

// ---- constants -------------------------------------------------------------
#define BB 64
#define SS 200
#define DM 1024
#define NH 16
#define MM (BB * SS)          // 12800
#define OUT0_ELEMS (MM * DM)  // 13107200

// ---- helpers ---------------------------------------------------------------
__device__ static inline u16 f2bf(float f) {
    __bf16 h = (__bf16)f;                 // RNE convert
    return __builtin_bit_cast(u16, h);
}

__device__ static inline bf16x8 load8(const u16* p) {
    uint4 u = *(const uint4*)p;           // 16B vector load
    union { uint4 u; bf16x8 b; } cv; cv.u = u; return cv.b;
}

__device__ static inline bf16x8 bzero8() {
    union { uint4 u; bf16x8 b; } cv; cv.u = make_uint4(0u, 0u, 0u, 0u); return cv.b;
}

__device__ static inline void gload_lds16(const void* g, void* l) {
    __builtin_amdgcn_global_load_lds(
        (const __attribute__((address_space(1))) void*)g,
        (__attribute__((address_space(3))) void*)l, 16, 0, 0);
}

// ---- kernel 1: f32 -> bf16 conversion (x + 4 weight matrices) --------------
__global__ __launch_bounds__(256) void convert_k(
    const float* __restrict__ x,
    const float* __restrict__ wq, const float* __restrict__ wk,
    const float* __restrict__ wv, const float* __restrict__ wo,
    u16* __restrict__ xb,
    u16* __restrict__ wqb, u16* __restrict__ wkb,
    u16* __restrict__ wvb, u16* __restrict__ wob)
{
    size_t i4 = (size_t)blockIdx.x * 256 + threadIdx.x;
    size_t e = i4 * 4;
    const float* src; u16* dst; size_t off;
    if (e < (size_t)OUT0_ELEMS) { src = x; dst = xb; off = e; }
    else {
        size_t we = e - OUT0_ELEMS;
        size_t w = we >> 20;              // each weight = 1048576 elems
        off = we & 1048575u;
        src = (w == 0) ? wq : (w == 1) ? wk : (w == 2) ? wv : wo;
        dst = (w == 0) ? wqb : (w == 1) ? wkb : (w == 2) ? wvb : wob;
    }
    float4 v = *(const float4*)(src + off);
    union { u16 s[4]; uint2 u; } o;
    o.s[0] = f2bf(v.x); o.s[1] = f2bf(v.y); o.s[2] = f2bf(v.z); o.s[3] = f2bf(v.w);
    *(uint2*)(dst + off) = o.u;
}

// ---- kernel 1b: mask [64,1,200,200] int32 -> bit-packed 4 u64 per row ------
__global__ __launch_bounds__(256) void maskbits_k(
    const int* __restrict__ mask, u64* __restrict__ bits)
{
    __shared__ unsigned char nb[4][64];
    const int wave = threadIdx.x >> 6, lane = threadIdx.x & 63;
    const int row = blockIdx.x * 4 + wave;       // 0..12799 = b*200 + i
    const int* mp = mask + (size_t)row * 200;
    unsigned nib;
    if (lane < 50) {
        int4 v = *(const int4*)(mp + lane * 4);
        nib = (v.x ? 1u : 0u) | (v.y ? 2u : 0u) | (v.z ? 4u : 0u) | (v.w ? 8u : 0u);
    } else nib = 0xFu;                           // cols >= 200: unmasked (never used)
    nb[wave][lane] = (unsigned char)nib;
    __builtin_amdgcn_s_waitcnt(0);               // same-wave LDS ordering
    if (lane < 4) {
        const unsigned char* p = &nb[wave][lane * 16];
        u64 m = 0;
#pragma unroll
        for (int i = 0; i < 16; i++) m |= (u64)(p[i] & 0xFu) << (4 * i);
        bits[(size_t)row * 4 + lane] = m;
    }
}

// ---- kernel 2/5: 128x128 MFMA GEMM, A[M,1024] bf16 * W[N,1024]^T ----------
// MODE 0: fused QKV, W = [wq;wk;wv] (3072 rows). seg = n0>>10 selects output:
//   q,k -> row-major bf16 [12800][1024] via LDS-staged coalesced uint4 stores
//   v   -> [b,h,dk,s] transposed (uint2 stores along s)
// MODE 1: out-proj; epilogue adds bias, writes f32 row-major [M,1024].
template <int MODE>
__global__ __launch_bounds__(256) void gemm_k(
    const u16* __restrict__ A, const u16* __restrict__ W,
    const float* __restrict__ b0, const float* __restrict__ b1, const float* __restrict__ b2,
    u16* __restrict__ qo, u16* __restrict__ ko, u16* __restrict__ vto,
    float* __restrict__ outf)
{
    __shared__ __align__(16) u16 sm[8192];  // As(4096) + Bs(4096); reused as C-stage
    u16* As = sm;
    u16* Bs = sm + 4096;

    const int tid  = threadIdx.x;
    const int wave = tid >> 6;
    const int lane = tid & 63;
    const int quad = lane >> 4;
    const int l15  = lane & 15;
    const int n0   = blockIdx.x * 128;        // MODE0: 0..3071, MODE1: 0..1023
    const int m0   = blockIdx.y * 128;
    const int seg  = (MODE == 0) ? (n0 >> 10) : 0;
    const int nn0  = n0 & 1023;
    const float* bias = (MODE == 1) ? b0 : (seg == 0 ? b0 : (seg == 1 ? b1 : b2));

    const int srow = wave * 16 + (lane >> 2); // row within a 64-row half
    const int sk8  = (lane & 3) * 8;          // k-elem offset 0/8/16/24
    const int wuni = __builtin_amdgcn_readfirstlane(wave);

    f32x4 acc[4][4];
#pragma unroll
    for (int i = 0; i < 4; i++)
#pragma unroll
        for (int j = 0; j < 4; j++) acc[i][j] = (f32x4){0.f, 0.f, 0.f, 0.f};

    const int wr = (wave >> 1) * 64;  // wave row offset in 128-tile
    const int wc = (wave & 1) * 64;   // wave col offset

    const u16* Ag = A + (size_t)m0 * 1024;
    const u16* Wg = W + (size_t)n0 * 1024;

    for (int kc = 0; kc < 1024; kc += 32) {
        __syncthreads();
#pragma unroll
        for (int r = 0; r < 2; r++) {
            int row = r * 64 + srow;
            gload_lds16(Ag + (size_t)row * 1024 + kc + sk8, &As[(r * 64 + wuni * 16) * 32]);
        }
#pragma unroll
        for (int r = 0; r < 2; r++) {
            int row = r * 64 + srow;
            gload_lds16(Wg + (size_t)row * 1024 + kc + sk8, &Bs[(r * 64 + wuni * 16) * 32]);
        }
        __syncthreads();

        bf16x8 af[4], bf[4];
#pragma unroll
        for (int mt = 0; mt < 4; mt++) af[mt] = load8(&As[(wr + mt * 16 + l15) * 32 + quad * 8]);
#pragma unroll
        for (int nt = 0; nt < 4; nt++) bf[nt] = load8(&Bs[(wc + nt * 16 + l15) * 32 + quad * 8]);
#pragma unroll
        for (int mt = 0; mt < 4; mt++)
#pragma unroll
            for (int nt = 0; nt < 4; nt++)
                acc[mt][nt] = MFMA16(af[mt], bf[nt], acc[mt][nt]);
    }

    // epilogue  (C layout: col = lane&15, row = quad*4 + reg)
    if (MODE == 1) {
#pragma unroll
        for (int nt = 0; nt < 4; nt++) {
            int n = n0 + wc + nt * 16 + l15;
            float bv = bias[n];
#pragma unroll
            for (int mt = 0; mt < 4; mt++)
#pragma unroll
                for (int r = 0; r < 4; r++) {
                    int m = m0 + wr + mt * 16 + quad * 4 + r;
                    __builtin_nontemporal_store(acc[mt][nt][r] + bv,
                                                &outf[(size_t)m * 1024 + n]);
                }
        }
    } else if (seg == 2) {
        // v: lane holds 4 consecutive m(=s) at fixed n -> one uint2 per (mt,nt).
#pragma unroll
        for (int nt = 0; nt < 4; nt++) {
            int nn = nn0 + wc + nt * 16 + l15;
            float bv = bias[nn];
            int hh = nn >> 6, d = nn & 63;
#pragma unroll
            for (int mt = 0; mt < 4; mt++) {
                int mbase = m0 + wr + mt * 16 + quad * 4;
                int b = mbase / 200, s = mbase - b * 200;   // 200%4==0: no crossing
                union { u16 q[4]; uint2 u; } pk;
#pragma unroll
                for (int r = 0; r < 4; r++) pk.q[r] = f2bf(acc[mt][nt][r] + bv);
                *(uint2*)&vto[((size_t)(b * 16 + hh) * 64 + d) * 200 + s] = pk.u;
            }
        }
    } else {
        // q/k: stage C through LDS (two 64-row halves), coalesced uint4 stores.
        u16* dst = (seg == 0) ? qo : ko;
        float bv[4];
#pragma unroll
        for (int nt = 0; nt < 4; nt++) bv[nt] = bias[nn0 + wc + nt * 16 + l15];
#pragma unroll
        for (int h2 = 0; h2 < 2; h2++) {
            __syncthreads();
            if ((wave >> 1) == h2) {
#pragma unroll
                for (int nt = 0; nt < 4; nt++)
#pragma unroll
                    for (int mt = 0; mt < 4; mt++)
#pragma unroll
                        for (int r = 0; r < 4; r++) {
                            int rl = mt * 16 + quad * 4 + r;
                            int c  = wc + nt * 16 + l15;
                            sm[rl * 128 + (c ^ ((rl & 7) << 4))] = f2bf(acc[mt][nt][r] + bv[nt]);
                        }
            }
            __syncthreads();
#pragma unroll
            for (int j = 0; j < 4; j++) {
                int idx = tid + j * 256;
                int rl = idx >> 4, c8 = (idx & 15) * 8;
                int c8s = c8 ^ ((rl & 7) << 4);
                uint4 vv = *(const uint4*)&sm[rl * 128 + c8s];
                *(uint4*)&dst[((size_t)(m0 + h2 * 64 + rl)) * 1024 + nn0 + c8] = vv;
            }
        }
    }
}

// ---- kernel 3: fused attention, one 16-row tile per wave -------------------
// q,k row-major [b*200+s][1024] (col = h*64+d); vt [bh][d][s].
// Dense task map: 13 tiles/bh * 1024 bh = 13312 wave-tasks, 4 waves/block.
// Phase A: QK^T MFMA; bias+mask+max applied IN REGISTERS in C-layout
//          (row = quad*4+r held across the 16 l15-lanes -> shfl_xor reduce).
// Phase B: exp/sum/normalize in registers; nt f32 attn stores; bf16 P -> LDS.
// Phase C: PV MFMA from LDS A-frags + global vt B-frags; coalesced ctx out.
__global__ __launch_bounds__(256, 4) void attn_k(
    const u16* __restrict__ qg, const u16* __restrict__ kg, const u16* __restrict__ vtg,
    const u64* __restrict__ mbits,
    float* __restrict__ attn_out, u16* __restrict__ ctxb)
{
    // 6656 B/wave (bf16 P-tile only) -> 26624 B/block
    __shared__ __align__(16) u16 Pb[4][16 * 208];

    const int tid  = threadIdx.x;
    const int wave = tid >> 6;
    const int lane = tid & 63;
    const int quad = lane >> 4;
    const int l15  = lane & 15;

    const int task = blockIdx.x * 4 + wave;      // < 13312
    const int bh   = task / 13;                  // const divisor -> magic mul
    const int i0   = (task - bh * 13) * 16;      // 0..192
    const int b    = bh >> 4;
    const int h    = bh & 15;

    u16* pb = Pb[wave];

    // ---- Q A-frags (row = l15)
    const u16* qkbase = qg + (size_t)b * 200 * 1024 + h * 64;
    int qi = i0 + l15;
    const u16* qrow = qkbase + (size_t)(qi < 200 ? qi : 0) * 1024;
    bf16x8 aq0, aq1;
    if (qi < 200) { aq0 = load8(qrow + quad * 8); aq1 = load8(qrow + 32 + quad * 8); }
    else          { aq0 = bzero8(); aq1 = bzero8(); }

    const int ib = i0 + quad * 4;                // first of this lane's 4 rows
    const u16* kbase = kg + (size_t)b * 200 * 1024 + h * 64;
    const u64* mrow = mbits + (size_t)b * 200 * 4;
    const float TBC = -0.1f / 200.0f;            // analytic temporal bias coeff

    // ---- phase A: scores in registers (C layout: row=quad*4+r, col=t*16+l15)
    f32x4 sv[13];
    f32x4 mxr = (f32x4){-3.0e38f, -3.0e38f, -3.0e38f, -3.0e38f};
    u64 mw[4];

#pragma unroll
    for (int t = 0; t < 13; t++) {
        int kj = t * 16 + l15;
        const u16* krow = kbase + (size_t)(kj < 200 ? kj : 0) * 1024;
        bf16x8 bk0, bk1;
        if (kj < 200) { bk0 = load8(krow + quad * 8); bk1 = load8(krow + 32 + quad * 8); }
        else          { bk0 = bzero8(); bk1 = bzero8(); }
        f32x4 z = (f32x4){0.f, 0.f, 0.f, 0.f};
        z = MFMA16(aq0, bk0, z);
        z = MFMA16(aq1, bk1, z);

        if ((t & 3) == 0) {                      // refresh 64-col mask chunk
            const int c = t >> 2;                // compile-time per unrolled t
#pragma unroll
            for (int r = 0; r < 4; r++) {
                int ia = ib + r;
                mw[r] = mrow[(size_t)(ia < 200 ? ia : 0) * 4 + c];
            }
        }
        const int col = t * 16 + l15;            // never crosses a 64-boundary
        const int sh  = (t & 3) * 16 + l15;
        const float fc = (float)col;
        f32x4 s;
#pragma unroll
        for (int r = 0; r < 4; r++) {
            int ia = ib + r;
            float val = z[r] * 0.125f + TBC * fabsf((float)ia - fc);
            if (!((mw[r] >> sh) & 1)) val = -1e9f;
            s[r] = (ia < 200 && col < 200) ? val : -3.0e38f;
            mxr[r] = fmaxf(mxr[r], s[r]);
        }
        sv[t] = s;
    }

    // row max across the 16 l15-lanes (quad bits untouched by masks 1..8)
#pragma unroll
    for (int m = 1; m < 16; m <<= 1)
#pragma unroll
        for (int r = 0; r < 4; r++)
            mxr[r] = fmaxf(mxr[r], __shfl_xor(mxr[r], m, 64));

    // ---- phase B: exp + sum + normalize, all in registers
    f32x4 sum = (f32x4){0.f, 0.f, 0.f, 0.f};
#pragma unroll
    for (int t = 0; t < 13; t++) {
        f32x4 s = sv[t];
#pragma unroll
        for (int r = 0; r < 4; r++) { s[r] = __expf(s[r] - mxr[r]); sum[r] += s[r]; }
        sv[t] = s;
    }
#pragma unroll
    for (int m = 1; m < 16; m <<= 1)
#pragma unroll
        for (int r = 0; r < 4; r++)
            sum[r] += __shfl_xor(sum[r], m, 64);

    f32x4 inv;
#pragma unroll
    for (int r = 0; r < 4; r++) inv[r] = (sum[r] > 0.f) ? 1.f / sum[r] : 0.f;

    float* aop = attn_out + (size_t)bh * 40000;
#pragma unroll
    for (int t = 0; t < 13; t++) {
        const int col = t * 16 + l15;
#pragma unroll
        for (int r = 0; r < 4; r++) {
            int ia = ib + r;
            float a = sv[t][r] * inv[r];
            pb[(quad * 4 + r) * 208 + col] = (col < 200) ? f2bf(a) : (u16)0;
            if (ia < 200 && col < 200)
                __builtin_nontemporal_store(a, aop + (size_t)ia * 200 + col);
        }
    }

    // ---- phase C: PV from LDS bf16 A-frags, global vt B-frags
    f32x4 ctx[4];
#pragma unroll
    for (int nt = 0; nt < 4; nt++) ctx[nt] = (f32x4){0.f, 0.f, 0.f, 0.f};
    const u16* vb = vtg + (size_t)bh * 64 * 200;
#pragma unroll
    for (int kc = 0; kc < 224; kc += 32) {
        int j0 = kc + quad * 8;
        bf16x8 af = (j0 < 208) ? load8(pb + l15 * 208 + j0) : bzero8();
#pragma unroll
        for (int nt = 0; nt < 4; nt++) {
            bf16x8 bvf = (j0 < 200) ? load8(vb + (nt * 16 + l15) * 200 + j0) : bzero8();
            ctx[nt] = MFMA16(af, bvf, ctx[nt]);
        }
    }

    // stage ctx (C layout) into pb, then coalesced uint4 copy-out
#pragma unroll
    for (int nt = 0; nt < 4; nt++)
#pragma unroll
        for (int r = 0; r < 4; r++)
            pb[(quad * 4 + r) * 208 + nt * 16 + l15] = f2bf(ctx[nt][r]);

#pragma unroll
    for (int k = 0; k < 2; k++) {
        int rr = k * 8 + (lane >> 3), ss = lane & 7;
        int ia = i0 + rr;
        uint4 val = *(const uint4*)&pb[rr * 208 + ss * 8];
        if (ia < 200)
            *(uint4*)&ctxb[((size_t)b * 200 + ia) * 1024 + h * 64 + ss * 8] = val;
    }
}

// ---- launch ----------------------------------------------------------------
extern "C" void kernel_launch(void* const* d_in, const int* in_sizes, int n_in,
                              void* d_out, int out_size, void* d_ws, size_t ws_size,
                              hipStream_t stream) {
    const float* x    = (const float*)d_in[0];
    const int*   mask = (const int*)d_in[1];
    const float* wq   = (const float*)d_in[2];
    const float* bq   = (const float*)d_in[3];
    const float* wk   = (const float*)d_in[4];
    const float* bk   = (const float*)d_in[5];
    const float* wv   = (const float*)d_in[6];
    const float* bv   = (const float*)d_in[7];
    const float* wo   = (const float*)d_in[8];
    const float* bo   = (const float*)d_in[9];

    float* out  = (float*)d_out;
    float* attn = out + OUT0_ELEMS;

    char* ws = (char*)d_ws;
    u16* xb    = (u16*)(ws);                    // 26,214,400 B
    u16* wqb   = (u16*)(ws + 26214400);         //  2,097,152 B  } contiguous ->
    u16* wkb   = (u16*)(ws + 28311552);         //               }  fused W [3072][1024]
    u16* wvb   = (u16*)(ws + 30408704);         //               }
    u16* wob   = (u16*)(ws + 32505856);
    u16* qb    = (u16*)(ws + 34603008);         // 26,214,400 B  [b*200+s][1024]
    u16* kb    = (u16*)(ws + 60817408);         // 26,214,400 B  [b*200+s][1024]
    u16* vtb   = (u16*)(ws + 87031808);         // 26,214,400 B  [b,h,dk,s]
    u16* ctxb  = (u16*)(ws + 113246208);        // 26,214,400 B  [b,s,h*dk]
    u64* mbits = (u64*)(ws + 139460608);        //    409,600 B  [b*200+i][4]
    // total: 139,870,208 B

    // 1) convert x + weights to bf16
    convert_k<<<dim3(16896), dim3(256), 0, stream>>>(x, wq, wk, wv, wo, xb, wqb, wkb, wvb, wob);

    // 1b) bit-pack mask
    maskbits_k<<<dim3(3200), dim3(256), 0, stream>>>(mask, mbits);

    // 2) fused QKV projection: N=3072 (24 tiles) x M=12800 (100 tiles)
    gemm_k<0><<<dim3(24, 100), dim3(256), 0, stream>>>(
        xb, wqb, bq, bk, bv, qb, kb, vtb, nullptr);

    // 3) fused attention: 13312 wave-tasks, 4 waves/block -> 3328 blocks
    attn_k<<<dim3(3328), dim3(256), 0, stream>>>(qb, kb, vtb, mbits, attn, ctxb);

    // 4) output projection
    gemm_k<1><<<dim3(8, 100), dim3(256), 0, stream>>>(
        ctxb, wob, bo, nullptr, nullptr, nullptr, nullptr, nullptr, out);
}

// Round 3
// 533.575 us; speedup vs baseline: 1.0593x; 1.0593x over previous
//
#include <hip/hip_runtime.h>
#include <stdint.h>

typedef unsigned short u16;
typedef unsigned long long u64;
typedef __bf16 bf16x8 __attribute__((ext_vector_type(8)));
typedef float f32x4 __attribute__((ext_vector_type(4)));

#define MFMA16(a, b, c) __builtin_amdgcn_mfma_f32_16x16x32_bf16((a), (b), (c), 0, 0, 0)

// ---- constants -------------------------------------------------------------
#define BB 64
#define SS 200
#define DM 1024
#define NH 16
#define MM (BB * SS)          // 12800
#define OUT0_ELEMS (MM * DM)  // 13107200

// ---- helpers ---------------------------------------------------------------
__device__ static inline u16 f2bf(float f) {
    __bf16 h = (__bf16)f;                 // RNE convert
    return __builtin_bit_cast(u16, h);
}

__device__ static inline bf16x8 load8(const u16* p) {
    uint4 u = *(const uint4*)p;           // 16B vector load
    union { uint4 u; bf16x8 b; } cv; cv.u = u; return cv.b;
}

__device__ static inline bf16x8 bzero8() {
    union { uint4 u; bf16x8 b; } cv; cv.u = make_uint4(0u, 0u, 0u, 0u); return cv.b;
}

__device__ static inline void gload_lds16(const void* g, void* l) {
    __builtin_amdgcn_global_load_lds(
        (const __attribute__((address_space(1))) void*)g,
        (__attribute__((address_space(3))) void*)l, 16, 0, 0);
}

// ---- kernel 1: f32 -> bf16 conversion (x + 4 weight matrices) --------------
__global__ __launch_bounds__(256) void convert_k(
    const float* __restrict__ x,
    const float* __restrict__ wq, const float* __restrict__ wk,
    const float* __restrict__ wv, const float* __restrict__ wo,
    u16* __restrict__ xb,
    u16* __restrict__ wqb, u16* __restrict__ wkb,
    u16* __restrict__ wvb, u16* __restrict__ wob)
{
    size_t i4 = (size_t)blockIdx.x * 256 + threadIdx.x;
    size_t e = i4 * 4;
    const float* src; u16* dst; size_t off;
    if (e < (size_t)OUT0_ELEMS) { src = x; dst = xb; off = e; }
    else {
        size_t we = e - OUT0_ELEMS;
        size_t w = we >> 20;              // each weight = 1048576 elems
        off = we & 1048575u;
        src = (w == 0) ? wq : (w == 1) ? wk : (w == 2) ? wv : wo;
        dst = (w == 0) ? wqb : (w == 1) ? wkb : (w == 2) ? wvb : wob;
    }
    float4 v = *(const float4*)(src + off);
    union { u16 s[4]; uint2 u; } o;
    o.s[0] = f2bf(v.x); o.s[1] = f2bf(v.y); o.s[2] = f2bf(v.z); o.s[3] = f2bf(v.w);
    *(uint2*)(dst + off) = o.u;
}

// ---- kernel 1b: mask [64,1,200,200] int32 -> bit-packed 4 u64 per row ------
__global__ __launch_bounds__(256) void maskbits_k(
    const int* __restrict__ mask, u64* __restrict__ bits)
{
    __shared__ unsigned char nb[4][64];
    const int wave = threadIdx.x >> 6, lane = threadIdx.x & 63;
    const int row = blockIdx.x * 4 + wave;       // 0..12799 = b*200 + i
    const int* mp = mask + (size_t)row * 200;
    unsigned nib;
    if (lane < 50) {
        int4 v = *(const int4*)(mp + lane * 4);
        nib = (v.x ? 1u : 0u) | (v.y ? 2u : 0u) | (v.z ? 4u : 0u) | (v.w ? 8u : 0u);
    } else nib = 0xFu;                           // cols >= 200: unmasked (never used)
    nb[wave][lane] = (unsigned char)nib;
    __builtin_amdgcn_s_waitcnt(0);               // same-wave LDS ordering
    if (lane < 4) {
        const unsigned char* p = &nb[wave][lane * 16];
        u64 m = 0;
#pragma unroll
        for (int i = 0; i < 16; i++) m |= (u64)(p[i] & 0xFu) << (4 * i);
        bits[(size_t)row * 4 + lane] = m;
    }
}

// ---- kernel 2/5: 128x128 MFMA GEMM, A[M,1024] bf16 * W[N,1024]^T ----------
// MODE 0: fused QKV, W = [wq;wk;wv] (3072 rows). seg = n0>>10 selects output:
//   q,k -> row-major bf16 [12800][1024] via LDS-staged coalesced uint4 stores
//   v   -> [b,h,dk,s] transposed (uint2 stores along s)
// MODE 1: out-proj; epilogue adds bias, writes f32 row-major [M,1024].
template <int MODE>
__global__ __launch_bounds__(256) void gemm_k(
    const u16* __restrict__ A, const u16* __restrict__ W,
    const float* __restrict__ b0, const float* __restrict__ b1, const float* __restrict__ b2,
    u16* __restrict__ qo, u16* __restrict__ ko, u16* __restrict__ vto,
    float* __restrict__ outf)
{
    __shared__ __align__(16) u16 sm[8192];  // As(4096) + Bs(4096); reused as C-stage
    u16* As = sm;
    u16* Bs = sm + 4096;

    const int tid  = threadIdx.x;
    const int wave = tid >> 6;
    const int lane = tid & 63;
    const int quad = lane >> 4;
    const int l15  = lane & 15;
    const int n0   = blockIdx.x * 128;        // MODE0: 0..3071, MODE1: 0..1023
    const int m0   = blockIdx.y * 128;
    const int seg  = (MODE == 0) ? (n0 >> 10) : 0;
    const int nn0  = n0 & 1023;
    const float* bias = (MODE == 1) ? b0 : (seg == 0 ? b0 : (seg == 1 ? b1 : b2));

    const int srow = wave * 16 + (lane >> 2); // row within a 64-row half
    const int sk8  = (lane & 3) * 8;          // k-elem offset 0/8/16/24
    const int wuni = __builtin_amdgcn_readfirstlane(wave);

    f32x4 acc[4][4];
#pragma unroll
    for (int i = 0; i < 4; i++)
#pragma unroll
        for (int j = 0; j < 4; j++) acc[i][j] = (f32x4){0.f, 0.f, 0.f, 0.f};

    const int wr = (wave >> 1) * 64;  // wave row offset in 128-tile
    const int wc = (wave & 1) * 64;   // wave col offset

    const u16* Ag = A + (size_t)m0 * 1024;
    const u16* Wg = W + (size_t)n0 * 1024;

    for (int kc = 0; kc < 1024; kc += 32) {
        __syncthreads();
#pragma unroll
        for (int r = 0; r < 2; r++) {
            int row = r * 64 + srow;
            gload_lds16(Ag + (size_t)row * 1024 + kc + sk8, &As[(r * 64 + wuni * 16) * 32]);
        }
#pragma unroll
        for (int r = 0; r < 2; r++) {
            int row = r * 64 + srow;
            gload_lds16(Wg + (size_t)row * 1024 + kc + sk8, &Bs[(r * 64 + wuni * 16) * 32]);
        }
        __syncthreads();

        bf16x8 af[4], bf[4];
#pragma unroll
        for (int mt = 0; mt < 4; mt++) af[mt] = load8(&As[(wr + mt * 16 + l15) * 32 + quad * 8]);
#pragma unroll
        for (int nt = 0; nt < 4; nt++) bf[nt] = load8(&Bs[(wc + nt * 16 + l15) * 32 + quad * 8]);
#pragma unroll
        for (int mt = 0; mt < 4; mt++)
#pragma unroll
            for (int nt = 0; nt < 4; nt++)
                acc[mt][nt] = MFMA16(af[mt], bf[nt], acc[mt][nt]);
    }

    // epilogue  (C layout: col = lane&15, row = quad*4 + reg)
    if (MODE == 1) {
#pragma unroll
        for (int nt = 0; nt < 4; nt++) {
            int n = n0 + wc + nt * 16 + l15;
            float bv = bias[n];
#pragma unroll
            for (int mt = 0; mt < 4; mt++)
#pragma unroll
                for (int r = 0; r < 4; r++) {
                    int m = m0 + wr + mt * 16 + quad * 4 + r;
                    __builtin_nontemporal_store(acc[mt][nt][r] + bv,
                                                &outf[(size_t)m * 1024 + n]);
                }
        }
    } else if (seg == 2) {
        // v: lane holds 4 consecutive m(=s) at fixed n -> one uint2 per (mt,nt).
#pragma unroll
        for (int nt = 0; nt < 4; nt++) {
            int nn = nn0 + wc + nt * 16 + l15;
            float bv = bias[nn];
            int hh = nn >> 6, d = nn & 63;
#pragma unroll
            for (int mt = 0; mt < 4; mt++) {
                int mbase = m0 + wr + mt * 16 + quad * 4;
                int b = mbase / 200, s = mbase - b * 200;   // 200%4==0: no crossing
                union { u16 q[4]; uint2 u; } pk;
#pragma unroll
                for (int r = 0; r < 4; r++) pk.q[r] = f2bf(acc[mt][nt][r] + bv);
                *(uint2*)&vto[((size_t)(b * 16 + hh) * 64 + d) * 200 + s] = pk.u;
            }
        }
    } else {
        // q/k: stage C through LDS (two 64-row halves), coalesced uint4 stores.
        u16* dst = (seg == 0) ? qo : ko;
        float bv[4];
#pragma unroll
        for (int nt = 0; nt < 4; nt++) bv[nt] = bias[nn0 + wc + nt * 16 + l15];
#pragma unroll
        for (int h2 = 0; h2 < 2; h2++) {
            __syncthreads();
            if ((wave >> 1) == h2) {
#pragma unroll
                for (int nt = 0; nt < 4; nt++)
#pragma unroll
                    for (int mt = 0; mt < 4; mt++)
#pragma unroll
                        for (int r = 0; r < 4; r++) {
                            int rl = mt * 16 + quad * 4 + r;
                            int c  = wc + nt * 16 + l15;
                            sm[rl * 128 + (c ^ ((rl & 7) << 4))] = f2bf(acc[mt][nt][r] + bv[nt]);
                        }
            }
            __syncthreads();
#pragma unroll
            for (int j = 0; j < 4; j++) {
                int idx = tid + j * 256;
                int rl = idx >> 4, c8 = (idx & 15) * 8;
                int c8s = c8 ^ ((rl & 7) << 4);
                uint4 vv = *(const uint4*)&sm[rl * 128 + c8s];
                *(uint4*)&dst[((size_t)(m0 + h2 * 64 + rl)) * 1024 + nn0 + c8] = vv;
            }
        }
    }
}

// ---- kernel 3: fused attention, one 16-row tile per wave -------------------
// q,k row-major [b*200+s][1024] (col = h*64+d); vt [bh][d][s].
// Dense task map: 13 tiles/bh * 1024 bh = 13312 wave-tasks, 4 waves/block.
// LATENCY-PIPELINED: depth-4 k-frag prefetch in phase A, mask chunk
// double-buffer, depth-2 vt/P ping-pong in phase C, vt loads issued before
// the attn f32 store burst.  amdgpu_waves_per_eu(3,4): VGPR cap 170, target
// ~4 waves/SIMD (round-2 counters showed VGPR=64 starved all pipelining).
__global__ __launch_bounds__(256) __attribute__((amdgpu_waves_per_eu(3, 4)))
void attn_k(
    const u16* __restrict__ qg, const u16* __restrict__ kg, const u16* __restrict__ vtg,
    const u64* __restrict__ mbits,
    float* __restrict__ attn_out, u16* __restrict__ ctxb)
{
    // 6656 B/wave (bf16 P-tile only) -> 26624 B/block
    __shared__ __align__(16) u16 Pb[4][16 * 208];

    const int tid  = threadIdx.x;
    const int wave = tid >> 6;
    const int lane = tid & 63;
    const int quad = lane >> 4;
    const int l15  = lane & 15;

    const int task = blockIdx.x * 4 + wave;      // < 13312
    const int bh   = task / 13;                  // const divisor -> magic mul
    const int i0   = (task - bh * 13) * 16;      // 0..192
    const int b    = bh >> 4;
    const int h    = bh & 15;

    u16* pb = Pb[wave];

    // ---- Q A-frags (row = l15)
    const u16* qkbase = qg + (size_t)b * 200 * 1024 + h * 64;
    int qi = i0 + l15;
    const u16* qrow = qkbase + (size_t)(qi < 200 ? qi : 0) * 1024;
    bf16x8 aq0, aq1;
    if (qi < 200) { aq0 = load8(qrow + quad * 8); aq1 = load8(qrow + 32 + quad * 8); }
    else          { aq0 = bzero8(); aq1 = bzero8(); }

    const int ib = i0 + quad * 4;                // first of this lane's 4 rows
    const u16* kbase = kg + (size_t)b * 200 * 1024 + h * 64;
    const u64* mrow = mbits + (size_t)b * 200 * 4;
    const float TBC = -0.1f / 200.0f;            // analytic temporal bias coeff

    // k-frag prefetch, depth 4 (indices compile-time under full unroll)
#define KLOAD(T, A, B) do {                                              \
        int kj_ = (T) * 16 + l15;                                        \
        const u16* kr_ = kbase + (size_t)(kj_ < 200 ? kj_ : 0) * 1024;   \
        if (kj_ < 200) { (A) = load8(kr_ + quad * 8);                    \
                         (B) = load8(kr_ + 32 + quad * 8); }             \
        else           { (A) = bzero8(); (B) = bzero8(); }               \
    } while (0)

    // mask 64-col chunk load (4 rows/lane)
#define MLD(R, C) mrow[(size_t)((ib + (R)) < 200 ? (ib + (R)) : 0) * 4 + (C)]
#define LOADM(C, D) do { D[0] = MLD(0, C); D[1] = MLD(1, C);             \
                         D[2] = MLD(2, C); D[3] = MLD(3, C); } while (0)

    bf16x8 ka[4], kb4[4];
    KLOAD(0, ka[0], kb4[0]);
    KLOAD(1, ka[1], kb4[1]);
    KLOAD(2, ka[2], kb4[2]);
    KLOAD(3, ka[3], kb4[3]);

    u64 mwc[4], mwn[4];
    LOADM(0, mwc);

    // ---- phase A: scores in registers (C layout: row=quad*4+r, col=t*16+l15)
    f32x4 sv[13];
    f32x4 mxr = (f32x4){-3.0e38f, -3.0e38f, -3.0e38f, -3.0e38f};

#pragma unroll
    for (int t = 0; t < 13; t++) {
        bf16x8 b0 = ka[t & 3], b1 = kb4[t & 3];
        if (t + 4 < 13) KLOAD(t + 4, ka[t & 3], kb4[t & 3]);   // prefetch
        if ((t & 3) == 0 && (t >> 2) < 3) LOADM((t >> 2) + 1, mwn);  // next chunk

        f32x4 z = (f32x4){0.f, 0.f, 0.f, 0.f};
        z = MFMA16(aq0, b0, z);
        z = MFMA16(aq1, b1, z);

        const int col = t * 16 + l15;            // never crosses a 64-boundary
        const int sh  = (t & 3) * 16 + l15;
        const float fc = (float)col;
        f32x4 s;
#pragma unroll
        for (int r = 0; r < 4; r++) {
            int ia = ib + r;
            float val = z[r] * 0.125f + TBC * fabsf((float)ia - fc);
            if (!((mwc[r] >> sh) & 1)) val = -1e9f;
            s[r] = (ia < 200 && col < 200) ? val : -3.0e38f;
            mxr[r] = fmaxf(mxr[r], s[r]);
        }
        sv[t] = s;

        if ((t & 3) == 3) { mwc[0] = mwn[0]; mwc[1] = mwn[1];
                            mwc[2] = mwn[2]; mwc[3] = mwn[3]; }
    }

    // row max across the 16 l15-lanes (quad bits untouched by masks 1..8)
#pragma unroll
    for (int m = 1; m < 16; m <<= 1)
#pragma unroll
        for (int r = 0; r < 4; r++)
            mxr[r] = fmaxf(mxr[r], __shfl_xor(mxr[r], m, 64));

    // ---- phase B: exp + sum + normalize, all in registers
    f32x4 sum = (f32x4){0.f, 0.f, 0.f, 0.f};
#pragma unroll
    for (int t = 0; t < 13; t++) {
        f32x4 s = sv[t];
#pragma unroll
        for (int r = 0; r < 4; r++) { s[r] = __expf(s[r] - mxr[r]); sum[r] += s[r]; }
        sv[t] = s;
    }
#pragma unroll
    for (int m = 1; m < 16; m <<= 1)
#pragma unroll
        for (int r = 0; r < 4; r++)
            sum[r] += __shfl_xor(sum[r], m, 64);

    f32x4 inv;
#pragma unroll
    for (int r = 0; r < 4; r++) inv[r] = (sum[r] > 0.f) ? 1.f / sum[r] : 0.f;

    // ---- phase C prefetch slot 0 issued BEFORE the attn store burst so the
    // first PV MFMA waits vmcnt(~52) instead of draining the store queue.
    const u16* vb = vtg + (size_t)bh * 64 * 200;
    bf16x8 vf[2][4], afr[2];

#define VLOADF(KC7, BUF) do {                                            \
        int j0v_ = (KC7) * 32 + quad * 8;                                \
        if (j0v_ < 200) {                                                \
            vf[BUF][0] = load8(vb + (0 * 16 + l15) * 200 + j0v_);        \
            vf[BUF][1] = load8(vb + (1 * 16 + l15) * 200 + j0v_);        \
            vf[BUF][2] = load8(vb + (2 * 16 + l15) * 200 + j0v_);        \
            vf[BUF][3] = load8(vb + (3 * 16 + l15) * 200 + j0v_);        \
        } else { vf[BUF][0] = bzero8(); vf[BUF][1] = bzero8();           \
                 vf[BUF][2] = bzero8(); vf[BUF][3] = bzero8(); }         \
    } while (0)
#define AFLOAD(KC7, BUF) do {                                            \
        int j0a_ = (KC7) * 32 + quad * 8;                                \
        afr[BUF] = (j0a_ < 208) ? load8(pb + l15 * 208 + j0a_) : bzero8(); \
    } while (0)

    VLOADF(0, 0);

    float* aop = attn_out + (size_t)bh * 40000;
#pragma unroll
    for (int t = 0; t < 13; t++) {
        const int col = t * 16 + l15;
#pragma unroll
        for (int r = 0; r < 4; r++) {
            int ia = ib + r;
            float a = sv[t][r] * inv[r];
            pb[(quad * 4 + r) * 208 + col] = (col < 200) ? f2bf(a) : (u16)0;
            if (ia < 200 && col < 200)
                __builtin_nontemporal_store(a, aop + (size_t)ia * 200 + col);
        }
    }

    AFLOAD(0, 0);

    // ---- phase C: PV, depth-2 ping-pong on vt frags + P LDS read
    f32x4 ctx[4];
#pragma unroll
    for (int nt = 0; nt < 4; nt++) ctx[nt] = (f32x4){0.f, 0.f, 0.f, 0.f};

#pragma unroll
    for (int k7 = 0; k7 < 7; k7++) {
        if (k7 < 6) { VLOADF(k7 + 1, (k7 + 1) & 1); AFLOAD(k7 + 1, (k7 + 1) & 1); }
        ctx[0] = MFMA16(afr[k7 & 1], vf[k7 & 1][0], ctx[0]);
        ctx[1] = MFMA16(afr[k7 & 1], vf[k7 & 1][1], ctx[1]);
        ctx[2] = MFMA16(afr[k7 & 1], vf[k7 & 1][2], ctx[2]);
        ctx[3] = MFMA16(afr[k7 & 1], vf[k7 & 1][3], ctx[3]);
    }

    // stage ctx (C layout) into pb, then coalesced uint4 copy-out
#pragma unroll
    for (int nt = 0; nt < 4; nt++)
#pragma unroll
        for (int r = 0; r < 4; r++)
            pb[(quad * 4 + r) * 208 + nt * 16 + l15] = f2bf(ctx[nt][r]);

#pragma unroll
    for (int k = 0; k < 2; k++) {
        int rr = k * 8 + (lane >> 3), ss = lane & 7;
        int ia = i0 + rr;
        uint4 val = *(const uint4*)&pb[rr * 208 + ss * 8];
        if (ia < 200)
            *(uint4*)&ctxb[((size_t)b * 200 + ia) * 1024 + h * 64 + ss * 8] = val;
    }
}

// ---- launch ----------------------------------------------------------------
extern "C" void kernel_launch(void* const* d_in, const int* in_sizes, int n_in,
                              void* d_out, int out_size, void* d_ws, size_t ws_size,
                              hipStream_t stream) {
    const float* x    = (const float*)d_in[0];
    const int*   mask = (const int*)d_in[1];
    const float* wq   = (const float*)d_in[2];
    const float* bq   = (const float*)d_in[3];
    const float* wk   = (const float*)d_in[4];
    const float* bk   = (const float*)d_in[5];
    const float* wv   = (const float*)d_in[6];
    const float* bv   = (const float*)d_in[7];
    const float* wo   = (const float*)d_in[8];
    const float* bo   = (const float*)d_in[9];

    float* out  = (float*)d_out;
    float* attn = out + OUT0_ELEMS;

    char* ws = (char*)d_ws;
    u16* xb    = (u16*)(ws);                    // 26,214,400 B
    u16* wqb   = (u16*)(ws + 26214400);         //  2,097,152 B  } contiguous ->
    u16* wkb   = (u16*)(ws + 28311552);         //               }  fused W [3072][1024]
    u16* wvb   = (u16*)(ws + 30408704);         //               }
    u16* wob   = (u16*)(ws + 32505856);
    u16* qb    = (u16*)(ws + 34603008);         // 26,214,400 B  [b*200+s][1024]
    u16* kb    = (u16*)(ws + 60817408);         // 26,214,400 B  [b*200+s][1024]
    u16* vtb   = (u16*)(ws + 87031808);         // 26,214,400 B  [b,h,dk,s]
    u16* ctxb  = (u16*)(ws + 113246208);        // 26,214,400 B  [b,s,h*dk]
    u64* mbits = (u64*)(ws + 139460608);        //    409,600 B  [b*200+i][4]
    // total: 139,870,208 B

    // 1) convert x + weights to bf16
    convert_k<<<dim3(16896), dim3(256), 0, stream>>>(x, wq, wk, wv, wo, xb, wqb, wkb, wvb, wob);

    // 1b) bit-pack mask
    maskbits_k<<<dim3(3200), dim3(256), 0, stream>>>(mask, mbits);

    // 2) fused QKV projection: N=3072 (24 tiles) x M=12800 (100 tiles)
    gemm_k<0><<<dim3(24, 100), dim3(256), 0, stream>>>(
        xb, wqb, bq, bk, bv, qb, kb, vtb, nullptr);

    // 3) fused attention: 13312 wave-tasks, 4 waves/block -> 3328 blocks
    attn_k<<<dim3(3328), dim3(256), 0, stream>>>(qb, kb, vtb, mbits, attn, ctxb);

    // 4) output projection
    gemm_k<1><<<dim3(8, 100), dim3(256), 0, stream>>>(
        ctxb, wob, bo, nullptr, nullptr, nullptr, nullptr, nullptr, out);
}